// Round 1
// baseline (14914.934 us; speedup 1.0000x reference)
//
#include <hip/hip_runtime.h>
#include <hip/hip_fp16.h>

#define B_ 256
#define S_ 512
#define D_ 200
#define H_ 256

typedef _Float16 half4_t __attribute__((ext_vector_type(4)));
typedef _Float16 half8_t __attribute__((ext_vector_type(8)));
typedef float    floatx4 __attribute__((ext_vector_type(4)));

#define AGENT __HIP_MEMORY_SCOPE_AGENT

__device__ __forceinline__ float fast_sig(float x) {
    return 1.f / (1.f + __expf(-x));
}
__device__ __forceinline__ float fast_tanh(float x) {
    x = fminf(15.f, fmaxf(-15.f, x));
    float e = __expf(2.f * x);
    return (e - 1.f) / (e + 1.f);
}

// ---------------------------------------------------------------------------
// prep: build fp16 weight layouts in workspace.
//   W4T [1024][224]: W4T[n][k] = Wg[k][j] (x-part rows 0..199, zero-padded)
//   WhT [1024][256]: WhT[n][k] = Wg[200+k][j] (h-part), n = g*256+j
// ---------------------------------------------------------------------------
__global__ void prep(const float* __restrict__ Wi, const float* __restrict__ Wf,
                     const float* __restrict__ Wo, const float* __restrict__ Wz,
                     _Float16* __restrict__ W4T, _Float16* __restrict__ WhT) {
    const int n = blockIdx.x;      // 0..1023
    const int t = threadIdx.x;     // 0..255
    const int g = n >> 8, j = n & 255;
    const float* Wg = (g == 0) ? Wi : (g == 1) ? Wf : (g == 2) ? Wo : Wz;
    if (t < 224)
        W4T[(size_t)n * 224 + t] = (t < D_) ? (_Float16)Wg[t * 256 + j] : (_Float16)0.f;
    WhT[(size_t)n * 256 + t] = (_Float16)Wg[(D_ + t) * 256 + j];
}

// ---------------------------------------------------------------------------
// gemm_x: G[m][n] = sum_k X[m][k]*W4T[n][k] + bias[n]   (plain layout,
// coalesced stores: consecutive l16 -> consecutive gcol).  UNCHANGED.
// ---------------------------------------------------------------------------
__global__ __launch_bounds__(256) void gemm_x(const float* __restrict__ X,
                                              const _Float16* __restrict__ W4T,
                                              const float* __restrict__ bi,
                                              const float* __restrict__ bfg,
                                              const float* __restrict__ bo,
                                              const float* __restrict__ bz,
                                              _Float16* __restrict__ G) {
    __shared__ __align__(16) _Float16 As[128][40];
    __shared__ __align__(16) _Float16 Bs[128][40];

    const int mt = blockIdx.x >> 3;
    const int nt = blockIdx.x & 7;
    const int m0 = mt * 128, n0 = nt * 128;
    const int tid  = threadIdx.x;
    const int lane = tid & 63, wave = tid >> 6;
    const int quad = lane >> 4, l16 = lane & 15;
    const int mq = (wave & 1) * 64, nq = (wave >> 1) * 64;

    floatx4 acc[4][4];
#pragma unroll
    for (int i = 0; i < 4; ++i)
#pragma unroll
        for (int j = 0; j < 4; ++j) acc[i][j] = (floatx4){0.f, 0.f, 0.f, 0.f};

    const int srow = tid >> 1;
    const int koff = (tid & 1) * 16;

    for (int kt = 0; kt < 7; ++kt) {
        const int k0 = kt * 32;
        {
            const int m = m0 + srow;
            const float* xr = X + (size_t)m * D_ + (k0 + koff);
            half8_t v0, v1;
            if (m < B_ * S_ - 1) {
                const floatx4* xp = (const floatx4*)xr;
                floatx4 f0 = xp[0], f1 = xp[1], f2 = xp[2], f3 = xp[3];
#pragma unroll
                for (int i = 0; i < 4; ++i) {
                    v0[i]     = (_Float16)f0[i];
                    v0[4 + i] = (_Float16)f1[i];
                    v1[i]     = (_Float16)f2[i];
                    v1[4 + i] = (_Float16)f3[i];
                }
            } else {
#pragma unroll
                for (int i = 0; i < 8; ++i) {
                    int k = k0 + koff + i;
                    v0[i] = (k < D_) ? (_Float16)xr[i] : (_Float16)0.f;
                }
#pragma unroll
                for (int i = 0; i < 8; ++i) {
                    int k = k0 + koff + 8 + i;
                    v1[i] = (k < D_) ? (_Float16)xr[8 + i] : (_Float16)0.f;
                }
            }
            *(half8_t*)&As[srow][koff]     = v0;
            *(half8_t*)&As[srow][koff + 8] = v1;
        }
        {
            const _Float16* wr = W4T + (size_t)(n0 + srow) * 224 + (k0 + koff);
            const half8_t* wp = (const half8_t*)wr;
            *(half8_t*)&Bs[srow][koff]     = wp[0];
            *(half8_t*)&Bs[srow][koff + 8] = wp[1];
        }
        __syncthreads();

        half8_t af[4], bf[4];
#pragma unroll
        for (int i = 0; i < 4; ++i) af[i] = *(const half8_t*)&As[mq + i * 16 + l16][quad * 8];
#pragma unroll
        for (int i = 0; i < 4; ++i) bf[i] = *(const half8_t*)&Bs[nq + i * 16 + l16][quad * 8];
#pragma unroll
        for (int mi = 0; mi < 4; ++mi)
#pragma unroll
            for (int ni = 0; ni < 4; ++ni)
                acc[mi][ni] = __builtin_amdgcn_mfma_f32_16x16x32_f16(af[mi], bf[ni], acc[mi][ni], 0, 0, 0);
        __syncthreads();
    }

#pragma unroll
    for (int ni = 0; ni < 4; ++ni) {
        const int gcol = n0 + nq + ni * 16 + l16;
        const int g = gcol >> 8, j = gcol & 255;
        const float bv = ((g == 0) ? bi : (g == 1) ? bfg : (g == 2) ? bo : bz)[j];
#pragma unroll
        for (int mi = 0; mi < 4; ++mi)
#pragma unroll
            for (int r = 0; r < 4; ++r) {
                const int grow = m0 + mq + mi * 16 + quad * 4 + r;
                G[(size_t)grow * 1024 + gcol] = (_Float16)(acc[mi][ni][r] + bv);
            }
    }
}

// ---------------------------------------------------------------------------
// zero_cnt: reset the pair-sync counters (runs after gemm_x, before lstm_rec2;
// cnt lives in the W4T region which is dead after gemm_x).
// ---------------------------------------------------------------------------
__global__ void zero_cnt(unsigned* __restrict__ cnt) {
    cnt[threadIdx.x] = 0;   // 256 counters = [128 pairs][2]
}

// ---------------------------------------------------------------------------
// lstm_rec2: PAIR-SPLIT recurrence. Two blocks (bid, bid^8 -> same XCD under
// round-robin heuristic) cooperate on batches (2g, 2g+1):
//   - block q owns gate-columns j in [128q, 128q+128) for all 4 gates
//   - both batches packed into MFMA N (col parity = batch) -> per-wave
//     MFMA count halves vs the broadcast version (32 vs 64 per step)
//   - ALL 32 A-fragments (4 gates x 8 k-tiles) fit in 128 VGPRs: the 128 KB
//     WLfrag LDS buffer and its 16 ds_read_b128/wave/step are gone
//   - own h-half exchanged via LDS; partner h-half via LLC with agent-scope
//     atomics (release atomicAdd counter / relaxed loads, probe prefetched
//     one step ahead so the spin is usually free)
//   - s==0 skips all MFMA (h_0 = 0), so no h-buffer zero-init is needed
// ---------------------------------------------------------------------------
__global__ __launch_bounds__(512, 2) void lstm_rec2(
    const _Float16* __restrict__ G,     // [B][S][1024] plain, bias folded
    const _Float16* __restrict__ WhT,   // [1024][256] fp16
    const float* __restrict__ mask,     // [B][S] fp32
    unsigned* __restrict__ cnt,         // [128][2] sync counters
    unsigned* __restrict__ hbuf,        // [128][2][2][2][64] u32 (g,q,par,bat,j/2)
    float* __restrict__ out)            // [B][256] fp32
{
    __shared__ __align__(16) unsigned hS32[2][2][64];   // [par][bat][j/2], 1 KB
    __shared__ float mS[2][S_];                          // 4 KB

    const int bid  = blockIdx.x;
    const int q    = (bid >> 3) & 1;                    // half index within pair
    const int g    = (bid & 7) | ((bid >> 4) << 3);     // pair id 0..127
    const int b0   = 2 * g;
    const int t    = threadIdx.x;                       // 0..511
    const int w    = t >> 6;                            // wave 0..7
    const int lane = t & 63;
    const int l16  = lane & 15, quad = lane >> 4;
    const int bat  = l16 & 1;                           // batch = N-col parity
    const int rp   = (l16 >> 1) & 1;                    // row-pair within C frag

    // A-frag indices: slots 0..3 = OWN k-chunk (k in [128q,128q+128)),
    // slots 4..7 = PARTNER k-chunk.
    const int s_lo = 16 * q + quad;
    const int s_hi = 16 - 16 * q + quad;

#define DECLA(gi) half8_t A##gi##_0, A##gi##_1, A##gi##_2, A##gi##_3, \
                          A##gi##_4, A##gi##_5, A##gi##_6, A##gi##_7
#define LOADA(gi) do {                                                          \
        const half8_t* p = (const half8_t*)(WhT +                               \
            (size_t)((gi) * 256 + 128 * q + 16 * w + l16) * 256);               \
        A##gi##_0 = p[s_lo];      A##gi##_1 = p[s_lo + 4];                      \
        A##gi##_2 = p[s_lo + 8];  A##gi##_3 = p[s_lo + 12];                     \
        A##gi##_4 = p[s_hi];      A##gi##_5 = p[s_hi + 4];                      \
        A##gi##_6 = p[s_hi + 8];  A##gi##_7 = p[s_hi + 12];                     \
        asm volatile("" : "+v"(A##gi##_0), "+v"(A##gi##_1), "+v"(A##gi##_2),    \
                          "+v"(A##gi##_3), "+v"(A##gi##_4), "+v"(A##gi##_5),    \
                          "+v"(A##gi##_6), "+v"(A##gi##_7));                    \
    } while (0)

    DECLA(0); DECLA(1); DECLA(2); DECLA(3);
    LOADA(0); LOADA(1); LOADA(2); LOADA(3);

    // stage mask rows for both batches
    mS[0][t] = mask[(size_t)b0 * S_ + t];
    mS[1][t] = mask[(size_t)(b0 + 1) * S_ + t];

    unsigned* cnt_own = cnt + 2 * g + q;
    unsigned* cnt_rem = cnt + 2 * g + (1 - q);
    const int own_base = g * 512 + q * 256;
    const int rem_base = g * 512 + (1 - q) * 256;

    // G gather: lane's 4 gate pre-activation half4s for (batch=bat, j=16w+4quad+r)
    const _Float16* Gb = G + ((size_t)(b0 + bat) << 19) + (128 * q + 16 * w + 4 * quad);
    half4_t N0, N1, N2, N3;
#define GLOAD(sidx) do { const _Float16* gp = Gb + ((size_t)(sidx) << 10);      \
        N0 = *(const half4_t*)(gp);       N1 = *(const half4_t*)(gp + 256);     \
        N2 = *(const half4_t*)(gp + 512); N3 = *(const half4_t*)(gp + 768);     \
    } while (0)

#define MFS(f, Bv)                                                              \
    C0 = __builtin_amdgcn_mfma_f32_16x16x32_f16(A0_##f, Bv, C0, 0, 0, 0);       \
    C1 = __builtin_amdgcn_mfma_f32_16x16x32_f16(A1_##f, Bv, C1, 0, 0, 0);       \
    C2 = __builtin_amdgcn_mfma_f32_16x16x32_f16(A2_##f, Bv, C2, 0, 0, 0);       \
    C3 = __builtin_amdgcn_mfma_f32_16x16x32_f16(A3_##f, Bv, C3, 0, 0, 0)

    GLOAD(0);
    float cst0 = 0.f, cst1 = 0.f, acc0 = 0.f, acc1 = 0.f, msum = 0.f;
    unsigned cprobe = 0;
    __syncthreads();

    for (int s = 0; s < S_; ++s) {
        const int par = s & 1;

        // C init from prefetched G gather (bias folded by gemm_x)
        floatx4 C0, C1, C2, C3;
#pragma unroll
        for (int k = 0; k < 4; ++k) {
            C0[k] = (float)N0[k]; C1[k] = (float)N1[k];
            C2[k] = (float)N2[k]; C3[k] = (float)N3[k];
        }
        // prefetch next step's G
        GLOAD((s < S_ - 1) ? s + 1 : s);

        if (s > 0) {
            // partner must have finished step s-1 (counter >= 8s). The probe
            // from last step usually already proves it (monotone counter).
            const unsigned tgt = 8u * (unsigned)s;
            if (cprobe < tgt)
                while (__hip_atomic_load(cnt_rem, __ATOMIC_RELAXED, AGENT) < tgt) {}
            asm volatile("" ::: "memory");

            // issue remote h loads FIRST so LLC latency hides under local MFMAs
            unsigned long long* rb = (unsigned long long*)
                (hbuf + rem_base + (par << 7) + (bat << 6)) + 2 * quad;
            union { unsigned long long u[2]; half8_t v; } R0, R1, R2, R3;
            R0.u[0] = __hip_atomic_load(rb + 0,  __ATOMIC_RELAXED, AGENT);
            R0.u[1] = __hip_atomic_load(rb + 1,  __ATOMIC_RELAXED, AGENT);
            R1.u[0] = __hip_atomic_load(rb + 8,  __ATOMIC_RELAXED, AGENT);
            R1.u[1] = __hip_atomic_load(rb + 9,  __ATOMIC_RELAXED, AGENT);
            R2.u[0] = __hip_atomic_load(rb + 16, __ATOMIC_RELAXED, AGENT);
            R2.u[1] = __hip_atomic_load(rb + 17, __ATOMIC_RELAXED, AGENT);
            R3.u[0] = __hip_atomic_load(rb + 24, __ATOMIC_RELAXED, AGENT);
            R3.u[1] = __hip_atomic_load(rb + 25, __ATOMIC_RELAXED, AGENT);

            // local B fragments: own h-half from LDS (bat-selected, broadcast)
            const unsigned* hl = &hS32[par][bat][0];
            half8_t BL0 = *(const half8_t*)(hl + 4 * quad);
            half8_t BL1 = *(const half8_t*)(hl + 16 + 4 * quad);
            half8_t BL2 = *(const half8_t*)(hl + 32 + 4 * quad);
            half8_t BL3 = *(const half8_t*)(hl + 48 + 4 * quad);

            MFS(0, BL0); MFS(1, BL1); MFS(2, BL2); MFS(3, BL3);
            MFS(4, R0.v); MFS(5, R1.v); MFS(6, R2.v); MFS(7, R3.v);
        }
        // prefetch partner progress for next step's check
        cprobe = __hip_atomic_load(cnt_rem, __ATOMIC_RELAXED, AGENT);

        // gates: lane owns (batch=bat, j = 16w+4quad+2rp and +1)
        const float m0 = mS[bat][s];
        float pi0 = rp ? C0[2] : C0[0], pi1 = rp ? C0[3] : C0[1];
        float pf0 = rp ? C1[2] : C1[0], pf1 = rp ? C1[3] : C1[1];
        float po0 = rp ? C2[2] : C2[0], po1 = rp ? C2[3] : C2[1];
        float pz0 = rp ? C3[2] : C3[0], pz1 = rp ? C3[3] : C3[1];
        const float i0 = fast_sig(pi0), f0 = fast_sig(pf0);
        const float o0 = fast_sig(po0), z0 = fast_tanh(pz0);
        const float i1 = fast_sig(pi1), f1 = fast_sig(pf1);
        const float o1 = fast_sig(po1), z1 = fast_tanh(pz1);
        cst0 = i0 * z0 + f0 * cst0;
        cst1 = i1 * z1 + f1 * cst1;
        const float h0 = o0 * fast_tanh(cst0);
        const float h1 = o1 * fast_tanh(cst1);
        acc0 += m0 * h0; acc1 += m0 * h1; msum += m0;

        // publish h_{s+1}: LDS (own half) + LLC export for partner
        const int par1 = (s + 1) & 1;
        union { _Float16 hh[2]; unsigned u32; } pk;
        pk.hh[0] = (_Float16)h0; pk.hh[1] = (_Float16)h1;
        const int jj = 8 * w + 2 * quad + rp;
        if (l16 < 4) {
            hS32[par1][bat][jj] = pk.u32;
            __hip_atomic_store(hbuf + own_base + (par1 << 7) + (bat << 6) + jj,
                               pk.u32, __ATOMIC_RELAXED, AGENT);
        }
        if (lane == 0)
            __hip_atomic_fetch_add(cnt_own, 1u, __ATOMIC_RELEASE, AGENT);
        __syncthreads();
    }
#undef DECLA
#undef LOADA
#undef GLOAD
#undef MFS

    if (l16 < 4) {
        const int jg = 128 * q + 16 * w + 4 * quad + 2 * rp;
        const float inv = 1.f / msum;
        out[(b0 + bat) * 256 + jg]     = acc0 * inv;
        out[(b0 + bat) * 256 + jg + 1] = acc1 * inv;
    }
}

extern "C" void kernel_launch(void* const* d_in, const int* in_sizes, int n_in,
                              void* d_out, int out_size, void* d_ws, size_t ws_size,
                              hipStream_t stream) {
    const float* X    = (const float*)d_in[0];
    const float* mask = (const float*)d_in[1];
    const float* Wi   = (const float*)d_in[2];
    const float* bi   = (const float*)d_in[3];
    const float* Wf   = (const float*)d_in[4];
    const float* bf   = (const float*)d_in[5];
    const float* Wo   = (const float*)d_in[6];
    const float* bo   = (const float*)d_in[7];
    const float* Wz   = (const float*)d_in[8];
    const float* bz   = (const float*)d_in[9];
    float* out = (float*)d_out;

    char* ws = (char*)d_ws;
    _Float16* G   = (_Float16*)ws;                                   // 268,435,456 B
    _Float16* W4T = (_Float16*)(ws + (size_t)B_ * S_ * 1024 * 2);    //     458,752 B
    _Float16* WhT = (_Float16*)(ws + (size_t)B_ * S_ * 1024 * 2 + (size_t)1024 * 224 * 2);
    // pair-sync state reuses the W4T region (dead after gemm_x): 1 KB cnt + 256 KB hbuf
    unsigned* cnt  = (unsigned*)W4T;
    unsigned* hbuf = (unsigned*)W4T + 256;

    hipLaunchKernelGGL(prep,      dim3(1024), dim3(256), 0, stream, Wi, Wf, Wo, Wz, W4T, WhT);
    hipLaunchKernelGGL(gemm_x,    dim3(8192), dim3(256), 0, stream, X, W4T, bi, bf, bo, bz, G);
    hipLaunchKernelGGL(zero_cnt,  dim3(1),    dim3(256), 0, stream, cnt);
    hipLaunchKernelGGL(lstm_rec2, dim3(256),  dim3(512), 0, stream, G, WhT, mask, cnt, hbuf, out);
}

// Round 2
// 1750.910 us; speedup vs baseline: 8.5184x; 8.5184x over previous
//
#include <hip/hip_runtime.h>
#include <hip/hip_fp16.h>

#define B_ 256
#define S_ 512
#define D_ 200
#define H_ 256

typedef _Float16 half4_t __attribute__((ext_vector_type(4)));
typedef _Float16 half8_t __attribute__((ext_vector_type(8)));
typedef float    floatx4 __attribute__((ext_vector_type(4)));

#define AGENT __HIP_MEMORY_SCOPE_AGENT

__device__ __forceinline__ float fast_sig(float x) {
    return 1.f / (1.f + __expf(-x));
}
__device__ __forceinline__ float fast_tanh(float x) {
    x = fminf(15.f, fmaxf(-15.f, x));
    float e = __expf(2.f * x);
    return (e - 1.f) / (e + 1.f);
}

// ---------------------------------------------------------------------------
// prep: build fp16 weight layouts in workspace.  (unchanged)
// ---------------------------------------------------------------------------
__global__ void prep(const float* __restrict__ Wi, const float* __restrict__ Wf,
                     const float* __restrict__ Wo, const float* __restrict__ Wz,
                     _Float16* __restrict__ W4T, _Float16* __restrict__ WhT) {
    const int n = blockIdx.x;      // 0..1023
    const int t = threadIdx.x;     // 0..255
    const int g = n >> 8, j = n & 255;
    const float* Wg = (g == 0) ? Wi : (g == 1) ? Wf : (g == 2) ? Wo : Wz;
    if (t < 224)
        W4T[(size_t)n * 224 + t] = (t < D_) ? (_Float16)Wg[t * 256 + j] : (_Float16)0.f;
    WhT[(size_t)n * 256 + t] = (_Float16)Wg[(D_ + t) * 256 + j];
}

// ---------------------------------------------------------------------------
// gemm_x: unchanged (verified, ~230us).
// ---------------------------------------------------------------------------
__global__ __launch_bounds__(256) void gemm_x(const float* __restrict__ X,
                                              const _Float16* __restrict__ W4T,
                                              const float* __restrict__ bi,
                                              const float* __restrict__ bfg,
                                              const float* __restrict__ bo,
                                              const float* __restrict__ bz,
                                              _Float16* __restrict__ G) {
    __shared__ __align__(16) _Float16 As[128][40];
    __shared__ __align__(16) _Float16 Bs[128][40];

    const int mt = blockIdx.x >> 3;
    const int nt = blockIdx.x & 7;
    const int m0 = mt * 128, n0 = nt * 128;
    const int tid  = threadIdx.x;
    const int lane = tid & 63, wave = tid >> 6;
    const int quad = lane >> 4, l16 = lane & 15;
    const int mq = (wave & 1) * 64, nq = (wave >> 1) * 64;

    floatx4 acc[4][4];
#pragma unroll
    for (int i = 0; i < 4; ++i)
#pragma unroll
        for (int j = 0; j < 4; ++j) acc[i][j] = (floatx4){0.f, 0.f, 0.f, 0.f};

    const int srow = tid >> 1;
    const int koff = (tid & 1) * 16;

    for (int kt = 0; kt < 7; ++kt) {
        const int k0 = kt * 32;
        {
            const int m = m0 + srow;
            const float* xr = X + (size_t)m * D_ + (k0 + koff);
            half8_t v0, v1;
            if (m < B_ * S_ - 1) {
                const floatx4* xp = (const floatx4*)xr;
                floatx4 f0 = xp[0], f1 = xp[1], f2 = xp[2], f3 = xp[3];
#pragma unroll
                for (int i = 0; i < 4; ++i) {
                    v0[i]     = (_Float16)f0[i];
                    v0[4 + i] = (_Float16)f1[i];
                    v1[i]     = (_Float16)f2[i];
                    v1[4 + i] = (_Float16)f3[i];
                }
            } else {
#pragma unroll
                for (int i = 0; i < 8; ++i) {
                    int k = k0 + koff + i;
                    v0[i] = (k < D_) ? (_Float16)xr[i] : (_Float16)0.f;
                }
#pragma unroll
                for (int i = 0; i < 8; ++i) {
                    int k = k0 + koff + 8 + i;
                    v1[i] = (k < D_) ? (_Float16)xr[8 + i] : (_Float16)0.f;
                }
            }
            *(half8_t*)&As[srow][koff]     = v0;
            *(half8_t*)&As[srow][koff + 8] = v1;
        }
        {
            const _Float16* wr = W4T + (size_t)(n0 + srow) * 224 + (k0 + koff);
            const half8_t* wp = (const half8_t*)wr;
            *(half8_t*)&Bs[srow][koff]     = wp[0];
            *(half8_t*)&Bs[srow][koff + 8] = wp[1];
        }
        __syncthreads();

        half8_t af[4], bf[4];
#pragma unroll
        for (int i = 0; i < 4; ++i) af[i] = *(const half8_t*)&As[mq + i * 16 + l16][quad * 8];
#pragma unroll
        for (int i = 0; i < 4; ++i) bf[i] = *(const half8_t*)&Bs[nq + i * 16 + l16][quad * 8];
#pragma unroll
        for (int mi = 0; mi < 4; ++mi)
#pragma unroll
            for (int ni = 0; ni < 4; ++ni)
                acc[mi][ni] = __builtin_amdgcn_mfma_f32_16x16x32_f16(af[mi], bf[ni], acc[mi][ni], 0, 0, 0);
        __syncthreads();
    }

#pragma unroll
    for (int ni = 0; ni < 4; ++ni) {
        const int gcol = n0 + nq + ni * 16 + l16;
        const int g = gcol >> 8, j = gcol & 255;
        const float bv = ((g == 0) ? bi : (g == 1) ? bfg : (g == 2) ? bo : bz)[j];
#pragma unroll
        for (int mi = 0; mi < 4; ++mi)
#pragma unroll
            for (int r = 0; r < 4; ++r) {
                const int grow = m0 + mq + mi * 16 + quad * 4 + r;
                G[(size_t)grow * 1024 + gcol] = (_Float16)(acc[mi][ni][r] + bv);
            }
    }
}

// ---------------------------------------------------------------------------
// zero_tags: reset the 256 pair tags ([128 pairs][2 halves]).
// ---------------------------------------------------------------------------
__global__ void zero_tags(unsigned* __restrict__ tagb) {
    tagb[threadIdx.x] = 0;
}

// ---------------------------------------------------------------------------
// lstm_rec3: pair-split recurrence with FENCE-FREE exchange.
//   vs rec2 (which was correct but 14x slow): no RELEASE/ACQUIRE anywhere --
//   the release atomicAdd caused a per-step per-block L2 writeback.  Now:
//   - publishers store h-words relaxed/agent (sc1 -> LLC, no cache maint)
//   - end-of-step __syncthreads() drains them (vmcnt(0) before s_barrier)
//   - t0 stores monotone tag=s relaxed at top of step s => data-before-tag
//   - consumer wave 0 polls partner tag (prefetched 1 step ahead, usually
//     free), bulk-loads the partner 512B h-half ONCE (64 x u64, 64x less
//     LLC traffic than rec2's per-lane gather), parks it in LDS; all waves
//     then read remote B-fragments from LDS exactly like the local half.
//   - h LDS buffers padded (stride 80 dwords) to kill rec2's bank conflicts
//   Compute core (A-frags, G gather, gate select, publish) verbatim rec2.
// ---------------------------------------------------------------------------
__global__ __launch_bounds__(512, 2) void lstm_rec3(
    const _Float16* __restrict__ G,     // [B][S][1024] plain, bias folded
    const _Float16* __restrict__ WhT,   // [1024][256] fp16
    const float* __restrict__ mask,     // [B][S] fp32
    unsigned* __restrict__ tagb,        // [128][2] monotone step tags
    unsigned* __restrict__ exch,        // [128][2 q][2 par][128] u32 h-words
    float* __restrict__ out)            // [B][256] fp32
{
    __shared__ __align__(16) unsigned hL[2][2][80];  // local h  [par][bat][pad80]
    __shared__ __align__(16) unsigned hR[2][2][80];  // remote h [par][bat][pad80]
    __shared__ float mS[2][S_];                      // 4 KB

    const int bid  = blockIdx.x;
    const int q    = (bid >> 3) & 1;                    // half index within pair
    const int g    = (bid & 7) | ((bid >> 4) << 3);     // pair id 0..127
    const int b0   = 2 * g;
    const int t    = threadIdx.x;
    const int w    = t >> 6;
    const int lane = t & 63;
    const int l16  = lane & 15, quad = lane >> 4;
    const int bat  = l16 & 1;
    const int rp   = (l16 >> 1) & 1;

    const int s_lo = 16 * q + quad;
    const int s_hi = 16 - 16 * q + quad;

#define DECLA(gi) half8_t A##gi##_0, A##gi##_1, A##gi##_2, A##gi##_3, \
                          A##gi##_4, A##gi##_5, A##gi##_6, A##gi##_7
#define LOADA(gi) do {                                                          \
        const half8_t* p = (const half8_t*)(WhT +                               \
            (size_t)((gi) * 256 + 128 * q + 16 * w + l16) * 256);               \
        A##gi##_0 = p[s_lo];      A##gi##_1 = p[s_lo + 4];                      \
        A##gi##_2 = p[s_lo + 8];  A##gi##_3 = p[s_lo + 12];                     \
        A##gi##_4 = p[s_hi];      A##gi##_5 = p[s_hi + 4];                      \
        A##gi##_6 = p[s_hi + 8];  A##gi##_7 = p[s_hi + 12];                     \
        asm volatile("" : "+v"(A##gi##_0), "+v"(A##gi##_1), "+v"(A##gi##_2),    \
                          "+v"(A##gi##_3), "+v"(A##gi##_4), "+v"(A##gi##_5),    \
                          "+v"(A##gi##_6), "+v"(A##gi##_7));                    \
    } while (0)

    DECLA(0); DECLA(1); DECLA(2); DECLA(3);
    LOADA(0); LOADA(1); LOADA(2); LOADA(3);

    mS[0][t] = mask[(size_t)b0 * S_ + t];
    mS[1][t] = mask[(size_t)(b0 + 1) * S_ + t];

    unsigned* tag_own = tagb + 2 * g + q;
    unsigned* tag_rem = tagb + 2 * g + (1 - q);
    unsigned* ebuf_own = exch + (size_t)(g * 2 + q) * 256;       // [par][128]
    unsigned* ebuf_rem = exch + (size_t)(g * 2 + (1 - q)) * 256;

    const _Float16* Gb = G + ((size_t)(b0 + bat) << 19) + (128 * q + 16 * w + 4 * quad);
    half4_t N0, N1, N2, N3;
#define GLOAD(sidx) do { const _Float16* gp = Gb + ((size_t)(sidx) << 10);      \
        N0 = *(const half4_t*)(gp);       N1 = *(const half4_t*)(gp + 256);     \
        N2 = *(const half4_t*)(gp + 512); N3 = *(const half4_t*)(gp + 768);     \
    } while (0)

#define MFS(f, Bv)                                                              \
    C0 = __builtin_amdgcn_mfma_f32_16x16x32_f16(A0_##f, Bv, C0, 0, 0, 0);       \
    C1 = __builtin_amdgcn_mfma_f32_16x16x32_f16(A1_##f, Bv, C1, 0, 0, 0);       \
    C2 = __builtin_amdgcn_mfma_f32_16x16x32_f16(A2_##f, Bv, C2, 0, 0, 0);       \
    C3 = __builtin_amdgcn_mfma_f32_16x16x32_f16(A3_##f, Bv, C3, 0, 0, 0)

    GLOAD(0);
    float cst0 = 0.f, cst1 = 0.f, acc0 = 0.f, acc1 = 0.f, msum = 0.f;
    unsigned tprobe = 0;
    __syncthreads();

    for (int s = 0; s < S_; ++s) {
        const int par = s & 1;

        // announce h_s valid (publisher stores drained by prev barrier's vmcnt(0))
        if (t == 0 && s > 0)
            __hip_atomic_store(tag_own, (unsigned)s, __ATOMIC_RELAXED, AGENT);

        floatx4 C0, C1, C2, C3;
#pragma unroll
        for (int k = 0; k < 4; ++k) {
            C0[k] = (float)N0[k]; C1[k] = (float)N1[k];
            C2[k] = (float)N2[k]; C3[k] = (float)N3[k];
        }
        GLOAD((s < S_ - 1) ? s + 1 : s);

        if (s > 0) {
            unsigned long long vrem = 0;
            if (w == 0) {
                const unsigned tgt = (unsigned)s;
                if (tprobe < tgt) {
                    do {
                        tprobe = __hip_atomic_load(tag_rem, __ATOMIC_RELAXED, AGENT);
                    } while (tprobe < tgt);
                }
                asm volatile("" ::: "memory");
                vrem = __hip_atomic_load(
                    (unsigned long long*)(ebuf_rem + (par << 7)) + lane,
                    __ATOMIC_RELAXED, AGENT);
            }

            // local B fragments (own h half) + local-half MFMAs
            const unsigned* hl = &hL[par][bat][0];
            half8_t BL0 = *(const half8_t*)(hl + 4 * quad);
            half8_t BL1 = *(const half8_t*)(hl + 16 + 4 * quad);
            half8_t BL2 = *(const half8_t*)(hl + 32 + 4 * quad);
            half8_t BL3 = *(const half8_t*)(hl + 48 + 4 * quad);
            MFS(0, BL0); MFS(1, BL1); MFS(2, BL2); MFS(3, BL3);

            // park remote half in LDS (vmcnt wait lands here, after local MFMAs)
            if (w == 0) {
                unsigned* hw = &hR[par][lane >> 5][2 * (lane & 31)];
                hw[0] = (unsigned)vrem;
                hw[1] = (unsigned)(vrem >> 32);
            }
            __syncthreads();   // barrier M: hR visible

            const unsigned* hr = &hR[par][bat][0];
            half8_t BR0 = *(const half8_t*)(hr + 4 * quad);
            half8_t BR1 = *(const half8_t*)(hr + 16 + 4 * quad);
            half8_t BR2 = *(const half8_t*)(hr + 32 + 4 * quad);
            half8_t BR3 = *(const half8_t*)(hr + 48 + 4 * quad);
            MFS(4, BR0); MFS(5, BR1); MFS(6, BR2); MFS(7, BR3);

            // prefetch partner progress for next step (latency hides in tail)
            if (w == 0)
                tprobe = __hip_atomic_load(tag_rem, __ATOMIC_RELAXED, AGENT);
        }

        // gates: lane owns (batch=bat, j = 128q + 16w + 4quad + 2rp, +1)
        const float m0 = mS[bat][s];
        float pi0 = rp ? C0[2] : C0[0], pi1 = rp ? C0[3] : C0[1];
        float pf0 = rp ? C1[2] : C1[0], pf1 = rp ? C1[3] : C1[1];
        float po0 = rp ? C2[2] : C2[0], po1 = rp ? C2[3] : C2[1];
        float pz0 = rp ? C3[2] : C3[0], pz1 = rp ? C3[3] : C3[1];
        const float i0 = fast_sig(pi0), f0 = fast_sig(pf0);
        const float o0 = fast_sig(po0), z0 = fast_tanh(pz0);
        const float i1 = fast_sig(pi1), f1 = fast_sig(pf1);
        const float o1 = fast_sig(po1), z1 = fast_tanh(pz1);
        cst0 = i0 * z0 + f0 * cst0;
        cst1 = i1 * z1 + f1 * cst1;
        const float h0 = o0 * fast_tanh(cst0);
        const float h1 = o1 * fast_tanh(cst1);
        acc0 += m0 * h0; acc1 += m0 * h1; msum += m0;

        // publish h_{s+1}: LDS (local) + relaxed LLC export (partner)
        const int par1 = (s + 1) & 1;
        union { _Float16 hh[2]; unsigned u32; } pk;
        pk.hh[0] = (_Float16)h0; pk.hh[1] = (_Float16)h1;
        const int jj = 8 * w + 2 * quad + rp;
        if (l16 < 4) {
            hL[par1][bat][jj] = pk.u32;
            __hip_atomic_store(ebuf_own + (par1 << 7) + (bat << 6) + jj,
                               pk.u32, __ATOMIC_RELAXED, AGENT);
        }
        __syncthreads();   // barrier E: hL visible, ebuf stores drained (vmcnt(0))
    }
#undef DECLA
#undef LOADA
#undef GLOAD
#undef MFS

    if (l16 < 4) {
        const int jg = 128 * q + 16 * w + 4 * quad + 2 * rp;
        const float inv = 1.f / msum;
        out[(b0 + bat) * 256 + jg]     = acc0 * inv;
        out[(b0 + bat) * 256 + jg + 1] = acc1 * inv;
    }
}

extern "C" void kernel_launch(void* const* d_in, const int* in_sizes, int n_in,
                              void* d_out, int out_size, void* d_ws, size_t ws_size,
                              hipStream_t stream) {
    const float* X    = (const float*)d_in[0];
    const float* mask = (const float*)d_in[1];
    const float* Wi   = (const float*)d_in[2];
    const float* bi   = (const float*)d_in[3];
    const float* Wf   = (const float*)d_in[4];
    const float* bf   = (const float*)d_in[5];
    const float* Wo   = (const float*)d_in[6];
    const float* bo   = (const float*)d_in[7];
    const float* Wz   = (const float*)d_in[8];
    const float* bz   = (const float*)d_in[9];
    float* out = (float*)d_out;

    char* ws = (char*)d_ws;
    _Float16* G   = (_Float16*)ws;                                   // 268,435,456 B
    _Float16* W4T = (_Float16*)(ws + (size_t)B_ * S_ * 1024 * 2);    //     458,752 B
    _Float16* WhT = (_Float16*)(ws + (size_t)B_ * S_ * 1024 * 2 + (size_t)1024 * 224 * 2);
    // exchange state overlays the W4T region (dead after gemm_x):
    //   tagb 1 KB + exch 256 KB  <=  448 KB
    unsigned* tagb = (unsigned*)W4T;
    unsigned* exch = (unsigned*)W4T + 256;

    hipLaunchKernelGGL(prep,      dim3(1024), dim3(256), 0, stream, Wi, Wf, Wo, Wz, W4T, WhT);
    hipLaunchKernelGGL(gemm_x,    dim3(8192), dim3(256), 0, stream, X, W4T, bi, bf, bo, bz, G);
    hipLaunchKernelGGL(zero_tags, dim3(1),    dim3(256), 0, stream, tagb);
    hipLaunchKernelGGL(lstm_rec3, dim3(256),  dim3(512), 0, stream, G, WhT, mask, tagb, exch, out);
}

// Round 3
// 1470.922 us; speedup vs baseline: 10.1399x; 1.1903x over previous
//
#include <hip/hip_runtime.h>
#include <hip/hip_fp16.h>

#define B_ 256
#define S_ 512
#define D_ 200
#define H_ 256

typedef _Float16 half4_t __attribute__((ext_vector_type(4)));
typedef _Float16 half8_t __attribute__((ext_vector_type(8)));
typedef float    floatx4 __attribute__((ext_vector_type(4)));
typedef unsigned long long u64;

#define AGENT __HIP_MEMORY_SCOPE_AGENT

__device__ __forceinline__ float fast_sig(float x) {
    return 1.f / (1.f + __expf(-x));
}
__device__ __forceinline__ float fast_tanh(float x) {
    x = fminf(15.f, fmaxf(-15.f, x));
    float e = __expf(2.f * x);
    return (e - 1.f) / (e + 1.f);
}

// ---------------------------------------------------------------------------
// prep: build fp16 weight layouts in workspace.  (unchanged)
// ---------------------------------------------------------------------------
__global__ void prep(const float* __restrict__ Wi, const float* __restrict__ Wf,
                     const float* __restrict__ Wo, const float* __restrict__ Wz,
                     _Float16* __restrict__ W4T, _Float16* __restrict__ WhT) {
    const int n = blockIdx.x;      // 0..1023
    const int t = threadIdx.x;     // 0..255
    const int g = n >> 8, j = n & 255;
    const float* Wg = (g == 0) ? Wi : (g == 1) ? Wf : (g == 2) ? Wo : Wz;
    if (t < 224)
        W4T[(size_t)n * 224 + t] = (t < D_) ? (_Float16)Wg[t * 256 + j] : (_Float16)0.f;
    WhT[(size_t)n * 256 + t] = (_Float16)Wg[(D_ + t) * 256 + j];
}

// ---------------------------------------------------------------------------
// gemm_x: unchanged (verified, ~230us).
// ---------------------------------------------------------------------------
__global__ __launch_bounds__(256) void gemm_x(const float* __restrict__ X,
                                              const _Float16* __restrict__ W4T,
                                              const float* __restrict__ bi,
                                              const float* __restrict__ bfg,
                                              const float* __restrict__ bo,
                                              const float* __restrict__ bz,
                                              _Float16* __restrict__ G) {
    __shared__ __align__(16) _Float16 As[128][40];
    __shared__ __align__(16) _Float16 Bs[128][40];

    const int mt = blockIdx.x >> 3;
    const int nt = blockIdx.x & 7;
    const int m0 = mt * 128, n0 = nt * 128;
    const int tid  = threadIdx.x;
    const int lane = tid & 63, wave = tid >> 6;
    const int quad = lane >> 4, l16 = lane & 15;
    const int mq = (wave & 1) * 64, nq = (wave >> 1) * 64;

    floatx4 acc[4][4];
#pragma unroll
    for (int i = 0; i < 4; ++i)
#pragma unroll
        for (int j = 0; j < 4; ++j) acc[i][j] = (floatx4){0.f, 0.f, 0.f, 0.f};

    const int srow = tid >> 1;
    const int koff = (tid & 1) * 16;

    for (int kt = 0; kt < 7; ++kt) {
        const int k0 = kt * 32;
        {
            const int m = m0 + srow;
            const float* xr = X + (size_t)m * D_ + (k0 + koff);
            half8_t v0, v1;
            if (m < B_ * S_ - 1) {
                const floatx4* xp = (const floatx4*)xr;
                floatx4 f0 = xp[0], f1 = xp[1], f2 = xp[2], f3 = xp[3];
#pragma unroll
                for (int i = 0; i < 4; ++i) {
                    v0[i]     = (_Float16)f0[i];
                    v0[4 + i] = (_Float16)f1[i];
                    v1[i]     = (_Float16)f2[i];
                    v1[4 + i] = (_Float16)f3[i];
                }
            } else {
#pragma unroll
                for (int i = 0; i < 8; ++i) {
                    int k = k0 + koff + i;
                    v0[i] = (k < D_) ? (_Float16)xr[i] : (_Float16)0.f;
                }
#pragma unroll
                for (int i = 0; i < 8; ++i) {
                    int k = k0 + koff + 8 + i;
                    v1[i] = (k < D_) ? (_Float16)xr[8 + i] : (_Float16)0.f;
                }
            }
            *(half8_t*)&As[srow][koff]     = v0;
            *(half8_t*)&As[srow][koff + 8] = v1;
        }
        {
            const _Float16* wr = W4T + (size_t)(n0 + srow) * 224 + (k0 + koff);
            const half8_t* wp = (const half8_t*)wr;
            *(half8_t*)&Bs[srow][koff]     = wp[0];
            *(half8_t*)&Bs[srow][koff + 8] = wp[1];
        }
        __syncthreads();

        half8_t af[4], bf[4];
#pragma unroll
        for (int i = 0; i < 4; ++i) af[i] = *(const half8_t*)&As[mq + i * 16 + l16][quad * 8];
#pragma unroll
        for (int i = 0; i < 4; ++i) bf[i] = *(const half8_t*)&Bs[nq + i * 16 + l16][quad * 8];
#pragma unroll
        for (int mi = 0; mi < 4; ++mi)
#pragma unroll
            for (int ni = 0; ni < 4; ++ni)
                acc[mi][ni] = __builtin_amdgcn_mfma_f32_16x16x32_f16(af[mi], bf[ni], acc[mi][ni], 0, 0, 0);
        __syncthreads();
    }

#pragma unroll
    for (int ni = 0; ni < 4; ++ni) {
        const int gcol = n0 + nq + ni * 16 + l16;
        const int g = gcol >> 8, j = gcol & 255;
        const float bv = ((g == 0) ? bi : (g == 1) ? bfg : (g == 2) ? bo : bz)[j];
#pragma unroll
        for (int mi = 0; mi < 4; ++mi)
#pragma unroll
            for (int r = 0; r < 4; ++r) {
                const int grow = m0 + mq + mi * 16 + quad * 4 + r;
                G[(size_t)grow * 1024 + gcol] = (_Float16)(acc[mi][ni][r] + bv);
            }
    }
}

// ---------------------------------------------------------------------------
// zero_exch: clear all 65536 exchange words.  MUST be agent-scope atomic
// stores (sc0|sc1 -> LLC): plain stores would sit dirty in one XCD's L2
// while consumers' sc1 loads read the (stale, previous-replay) LLC copy.
// ---------------------------------------------------------------------------
__global__ void zero_exch(u64* __restrict__ ebuf) {
    const int i = blockIdx.x * 512 + threadIdx.x;
    __hip_atomic_store(ebuf + i, 0ull, __ATOMIC_RELAXED, AGENT);
}

// ---------------------------------------------------------------------------
// lstm_rec4: pair-split recurrence, SELF-VALIDATING exchange (no tags).
//   Exchange word = u64 {lo32: 2xfp16 h, hi32: step}.  Single atomic
//   dwordx2 store => no tearing, no cross-thread ordering requirement.
//   - publish of h_s happens at TOP of step s (value held in regs across
//     the end-of-step barrier) => the LLC store ack has a full step of
//     slack before any barrier drains it (rec3 ate ~700cy/step here)
//   - consumer needs h_s mid-step s; it was stored at partner's step-s top
//     => ~a full local-MFMA phase of slack; spin is ~0 in lockstep (rec3's
//     same-phase tag cost a full LLC RT spin every step)
//   - producer can lead by at most 1 step (it must consume partner h_s
//     before publishing h_{s+1}) => 2-slot parity buffer is WAR-safe
//   - correctness independent of XCD placement (all exchange via LLC)
//   Compute core (A-frags, G gather, B-frags, gate select, out) verbatim
//   from the twice-verified rec2/rec3 core.
// ---------------------------------------------------------------------------
__global__ __launch_bounds__(512, 2) void lstm_rec4(
    const _Float16* __restrict__ G,     // [B][S][1024] plain, bias folded
    const _Float16* __restrict__ WhT,   // [1024][256] fp16
    const float* __restrict__ mask,     // [B][S] fp32
    u64* __restrict__ ebuf,             // [128][2 q][2 par][2 bat][64] u64
    float* __restrict__ out)            // [B][256] fp32
{
    __shared__ __align__(16) unsigned hL[2][2][80];  // local h  [par][bat][pad80]
    __shared__ __align__(16) unsigned hR[2][2][80];  // remote h [par][bat][pad80]
    __shared__ float mS[2][S_];                      // 4 KB

    const int bid  = blockIdx.x;
    const int q    = (bid >> 3) & 1;                    // half index within pair
    const int g    = (bid & 7) | ((bid >> 4) << 3);     // pair id 0..127
    const int b0   = 2 * g;
    const int t    = threadIdx.x;
    const int w    = t >> 6;
    const int lane = t & 63;
    const int l16  = lane & 15, quad = lane >> 4;
    const int bat  = l16 & 1;
    const int rp   = (l16 >> 1) & 1;

    const int s_lo = 16 * q + quad;
    const int s_hi = 16 - 16 * q + quad;

#define DECLA(gi) half8_t A##gi##_0, A##gi##_1, A##gi##_2, A##gi##_3, \
                          A##gi##_4, A##gi##_5, A##gi##_6, A##gi##_7
#define LOADA(gi) do {                                                          \
        const half8_t* p = (const half8_t*)(WhT +                               \
            (size_t)((gi) * 256 + 128 * q + 16 * w + l16) * 256);               \
        A##gi##_0 = p[s_lo];      A##gi##_1 = p[s_lo + 4];                      \
        A##gi##_2 = p[s_lo + 8];  A##gi##_3 = p[s_lo + 12];                     \
        A##gi##_4 = p[s_hi];      A##gi##_5 = p[s_hi + 4];                      \
        A##gi##_6 = p[s_hi + 8];  A##gi##_7 = p[s_hi + 12];                     \
        asm volatile("" : "+v"(A##gi##_0), "+v"(A##gi##_1), "+v"(A##gi##_2),    \
                          "+v"(A##gi##_3), "+v"(A##gi##_4), "+v"(A##gi##_5),    \
                          "+v"(A##gi##_6), "+v"(A##gi##_7));                    \
    } while (0)

    DECLA(0); DECLA(1); DECLA(2); DECLA(3);
    LOADA(0); LOADA(1); LOADA(2); LOADA(3);

    mS[0][t] = mask[(size_t)b0 * S_ + t];
    mS[1][t] = mask[(size_t)(b0 + 1) * S_ + t];

    u64* eb_own = ebuf + (size_t)(g * 2 + q) * 256;       // [2 par][2 bat][64]
    u64* eb_rem = ebuf + (size_t)(g * 2 + (1 - q)) * 256;

    const _Float16* Gb = G + ((size_t)(b0 + bat) << 19) + (128 * q + 16 * w + 4 * quad);
    half4_t N0, N1, N2, N3;
#define GLOAD(sidx) do { const _Float16* gp = Gb + ((size_t)(sidx) << 10);      \
        N0 = *(const half4_t*)(gp);       N1 = *(const half4_t*)(gp + 256);     \
        N2 = *(const half4_t*)(gp + 512); N3 = *(const half4_t*)(gp + 768);     \
    } while (0)

#define MFS(f, Bv)                                                              \
    C0 = __builtin_amdgcn_mfma_f32_16x16x32_f16(A0_##f, Bv, C0, 0, 0, 0);       \
    C1 = __builtin_amdgcn_mfma_f32_16x16x32_f16(A1_##f, Bv, C1, 0, 0, 0);       \
    C2 = __builtin_amdgcn_mfma_f32_16x16x32_f16(A2_##f, Bv, C2, 0, 0, 0);       \
    C3 = __builtin_amdgcn_mfma_f32_16x16x32_f16(A3_##f, Bv, C3, 0, 0, 0)

    GLOAD(0);
    float cst0 = 0.f, cst1 = 0.f, acc0 = 0.f, acc1 = 0.f, msum = 0.f;
    const int jj = 8 * w + 2 * quad + rp;   // publish word index (0..63)
    u64 pub = 0;                            // {h pair, step} held across barrier
    __syncthreads();

    for (int s = 0; s < S_; ++s) {
        const int par = s & 1;

        // 1) publish h_s (computed last iter) -- top of step => ack slack
        if (s > 0 && l16 < 4)
            __hip_atomic_store(eb_own + (par << 7) + (bat << 6) + jj, pub,
                               __ATOMIC_RELAXED, AGENT);

        // 2) C init from prefetched G gather; prefetch next step's G
        floatx4 C0, C1, C2, C3;
#pragma unroll
        for (int k = 0; k < 4; ++k) {
            C0[k] = (float)N0[k]; C1[k] = (float)N1[k];
            C2[k] = (float)N2[k]; C3[k] = (float)N3[k];
        }
        GLOAD((s < S_ - 1) ? s + 1 : s);

        if (s > 0) {
            // 3) issue remote h loads early (wave 0), consume after local MFMAs
            const u64* rb = eb_rem + ((size_t)par << 7) + 2 * lane;
            u64 w0v = 0, w1v = 0;
            if (w == 0) {
                w0v = __hip_atomic_load(rb,     __ATOMIC_RELAXED, AGENT);
                w1v = __hip_atomic_load(rb + 1, __ATOMIC_RELAXED, AGENT);
            }

            // 4) local-half B fragments + MFMAs (covers the LLC latency)
            const unsigned* hl = &hL[par][bat][0];
            half8_t BL0 = *(const half8_t*)(hl + 4 * quad);
            half8_t BL1 = *(const half8_t*)(hl + 16 + 4 * quad);
            half8_t BL2 = *(const half8_t*)(hl + 32 + 4 * quad);
            half8_t BL3 = *(const half8_t*)(hl + 48 + 4 * quad);
            MFS(0, BL0); MFS(1, BL1); MFS(2, BL2); MFS(3, BL3);

            // 5) validate step fields (spin ~0 in lockstep), park remote half
            if (w == 0) {
                const unsigned tgt = (unsigned)s;
                while ((unsigned)(w0v >> 32) != tgt)
                    w0v = __hip_atomic_load(rb, __ATOMIC_RELAXED, AGENT);
                while ((unsigned)(w1v >> 32) != tgt)
                    w1v = __hip_atomic_load(rb + 1, __ATOMIC_RELAXED, AGENT);
                unsigned* hw = &hR[par][lane >> 5][2 * (lane & 31)];
                hw[0] = (unsigned)w0v;
                hw[1] = (unsigned)w1v;
            }
            __syncthreads();   // barrier M: hR visible

            const unsigned* hr = &hR[par][bat][0];
            half8_t BR0 = *(const half8_t*)(hr + 4 * quad);
            half8_t BR1 = *(const half8_t*)(hr + 16 + 4 * quad);
            half8_t BR2 = *(const half8_t*)(hr + 32 + 4 * quad);
            half8_t BR3 = *(const half8_t*)(hr + 48 + 4 * quad);
            MFS(4, BR0); MFS(5, BR1); MFS(6, BR2); MFS(7, BR3);
        }

        // 6) gates: lane owns (batch=bat, j = 128q + 16w + 4quad + 2rp, +1)
        const float m0 = mS[bat][s];
        float pi0 = rp ? C0[2] : C0[0], pi1 = rp ? C0[3] : C0[1];
        float pf0 = rp ? C1[2] : C1[0], pf1 = rp ? C1[3] : C1[1];
        float po0 = rp ? C2[2] : C2[0], po1 = rp ? C2[3] : C2[1];
        float pz0 = rp ? C3[2] : C3[0], pz1 = rp ? C3[3] : C3[1];
        const float i0 = fast_sig(pi0), f0 = fast_sig(pf0);
        const float o0 = fast_sig(po0), z0 = fast_tanh(pz0);
        const float i1 = fast_sig(pi1), f1 = fast_sig(pf1);
        const float o1 = fast_sig(po1), z1 = fast_tanh(pz1);
        cst0 = i0 * z0 + f0 * cst0;
        cst1 = i1 * z1 + f1 * cst1;
        const float h0 = o0 * fast_tanh(cst0);
        const float h1 = o1 * fast_tanh(cst1);
        acc0 += m0 * h0; acc1 += m0 * h1; msum += m0;

        // 7) stage h_{s+1}: LDS now; global publish deferred to next step top
        const int par1 = (s + 1) & 1;
        union { _Float16 hh[2]; unsigned u32; } pk;
        pk.hh[0] = (_Float16)h0; pk.hh[1] = (_Float16)h1;
        if (l16 < 4)
            hL[par1][bat][jj] = pk.u32;
        pub = (u64)pk.u32 | ((u64)(unsigned)(s + 1) << 32);
        __syncthreads();   // barrier E: hL visible
    }
#undef DECLA
#undef LOADA
#undef GLOAD
#undef MFS

    if (l16 < 4) {
        const int jg = 128 * q + 16 * w + 4 * quad + 2 * rp;
        const float inv = 1.f / msum;
        out[(b0 + bat) * 256 + jg]     = acc0 * inv;
        out[(b0 + bat) * 256 + jg + 1] = acc1 * inv;
    }
}

extern "C" void kernel_launch(void* const* d_in, const int* in_sizes, int n_in,
                              void* d_out, int out_size, void* d_ws, size_t ws_size,
                              hipStream_t stream) {
    const float* X    = (const float*)d_in[0];
    const float* mask = (const float*)d_in[1];
    const float* Wi   = (const float*)d_in[2];
    const float* bi   = (const float*)d_in[3];
    const float* Wf   = (const float*)d_in[4];
    const float* bf   = (const float*)d_in[5];
    const float* Wo   = (const float*)d_in[6];
    const float* bo   = (const float*)d_in[7];
    const float* Wz   = (const float*)d_in[8];
    const float* bz   = (const float*)d_in[9];
    float* out = (float*)d_out;

    char* ws = (char*)d_ws;
    _Float16* G   = (_Float16*)ws;                                   // 268,435,456 B
    _Float16* W4T = (_Float16*)(ws + (size_t)B_ * S_ * 1024 * 2);    //     458,752 B
    _Float16* WhT = (_Float16*)(ws + (size_t)B_ * S_ * 1024 * 2 + (size_t)1024 * 224 * 2);
    // exchange buffer lives after WhT: 65536 u64 = 512 KB
    u64* ebuf = (u64*)(ws + (size_t)B_ * S_ * 1024 * 2
                          + (size_t)1024 * 224 * 2
                          + (size_t)1024 * 256 * 2);

    hipLaunchKernelGGL(prep,      dim3(1024), dim3(256), 0, stream, Wi, Wf, Wo, Wz, W4T, WhT);
    hipLaunchKernelGGL(gemm_x,    dim3(8192), dim3(256), 0, stream, X, W4T, bi, bf, bo, bz, G);
    hipLaunchKernelGGL(zero_exch, dim3(128),  dim3(512), 0, stream, ebuf);
    hipLaunchKernelGGL(lstm_rec4, dim3(256),  dim3(512), 0, stream, G, WhT, mask, ebuf, out);
}